// Round 2
// baseline (317.039 us; speedup 1.0000x reference)
//
#include <hip/hip_runtime.h>

typedef unsigned short u16;
typedef unsigned int u32;
typedef _Float16 f16;
typedef __attribute__((ext_vector_type(8))) _Float16 half8;
typedef __attribute__((ext_vector_type(2))) __fp16 fp16x2;
typedef __attribute__((ext_vector_type(4))) float float4_;
typedef __attribute__((ext_vector_type(4))) unsigned short ushort4_;
typedef __attribute__((ext_vector_type(4))) unsigned int u32x4;

union hu { f16 h; u16 u; };

__device__ __forceinline__ u32 pkrtz(float a, float b) {
    fp16x2 t = __builtin_amdgcn_cvt_pkrtz(a, b);
    union { fp16x2 h; u32 u; } cv; cv.h = t;
    return cv.u;
}

// ---------- async global->LDS, 16B/lane ----------
__device__ __forceinline__ void gl16(const u16* g, u16* l) {
    __builtin_amdgcn_global_load_lds(
        (const __attribute__((address_space(1))) void*)g,
        (__attribute__((address_space(3))) void*)l, 16, 0, 0);
}

#define Bsz 8
#define Tsz 4096
#define Csz 512
#define Usz 512
#define NG  1536           // 3U
#define KK  1024           // 2 taps * C
#define MM  32768          // B*T
#define NCH 128            // scan chunks (2 blocks/CU in scan kernels)
#define CHL 32             // chunk length

// ---------- P0: inputs fp32 -> fp16 plane [8][4097][512], zero row at t=4096 ----------
__global__ void prep_a(const float* __restrict__ in, u16* __restrict__ A16) {
    int gid = blockIdx.x * 256 + threadIdx.x;       // 2,097,664 threads, 8 halves each
    int idx8 = gid * 8;
    int c8 = idx8 & 511;
    int row = idx8 >> 9;                            // b*4097 + t
    int b = (u32)row / 4097u;
    int t = row - b * 4097;
    u32x4 w;
    if (t == Tsz) {
        w = (u32x4)0;
    } else {
        const float* p = in + ((size_t)(b * Tsz + t) << 9) + c8;
        float4_ v0 = *(const float4_*)p;
        float4_ v1 = *(const float4_*)(p + 4);
        w.x = pkrtz(v0.x, v0.y); w.y = pkrtz(v0.z, v0.w);
        w.z = pkrtz(v1.x, v1.y); w.w = pkrtz(v1.z, v1.w);
    }
    *(u32x4*)(A16 + idx8) = w;
}

// ---------- P1: weights [K=1024][N=1536] fp32 -> transposed fp16 [N][K] ----------
// LDS 64x64 transpose: coalesced fp32 reads, 8B/lane coalesced u16 writes.
// (old version: 1.5M scattered 2B stores at stride 2KB)
__global__ void prep_k(const float* __restrict__ kern, u16* __restrict__ KT) {
    __shared__ u16 t[64][70];                 // 70: spread banks on both phases
    const int k0 = blockIdx.x * 64;           // 16 blocks
    const int n0 = blockIdx.y * 64;           // 24 blocks
    const int tid = threadIdx.x;              // 256
    #pragma unroll
    for (int it = 0; it < 16; ++it) {
        int s = it * 256 + tid;
        int r = s >> 6;                        // k within tile
        int c = s & 63;                        // n within tile (coalesced)
        float v = kern[(size_t)(k0 + r) * NG + n0 + c];
        hu cv; cv.h = (f16)v;                  // RNE (same as old path)
        t[c][r] = cv.u;
    }
    __syncthreads();
    #pragma unroll
    for (int it = 0; it < 4; ++it) {
        int s = it * 256 + tid;
        int n = s >> 4;                        // row of KT tile
        int kq = (s & 15) * 4;                 // 4 u16 per lane, coalesced
        ushort4_ w;
        w.x = t[n][kq]; w.y = t[n][kq + 1]; w.z = t[n][kq + 2]; w.w = t[n][kq + 3];
        *(ushort4_*)(KT + (size_t)(n0 + n) * KK + k0 + kq) = w;
    }
}

// ---------- GEMM: gates = A'*K', fp16 MFMA ----------
// T3/T4/T5 structure: BM=128 BN=256 BK=64, 512 thr (8 waves 2Mx4N, wave tile 64x64),
// THREE LDS buffers (48KB each, 144KB total; gfx950 allows 160KB/WG) so tile kt+2
// is staged during tile kt with zero WAR hazard: at tile kt, reads hit buf kt%3,
// in-flight writes from tile kt-1 hit (kt+1)%3, new issues hit (kt+2)%3 -- disjoint.
// Main-loop gate is counted vmcnt(6) (tile kt's 6 loads are the per-wave oldest;
// vmcnt retires in issue order) -- never 0 except the last tile.
// Two 16-MFMA phases per K-tile, raw s_barrier + setprio(1).
// XOR-swizzled LDS (chunk c of row r at c^(r&7)) via pre-swizzled global source:
// ds_read_b128 bank-conflict-free (0 conflicts measured on this layout in R0).
#define LDS_A 8192         // u16 per A buffer (128x64)
#define LDS_B 16384        // u16 per B buffer (256x64)

__device__ __forceinline__ void stage_A(const u16* __restrict__ A16, u16* dst,
                                        int arow_base, int kin, int tid, int lane) {
    #pragma unroll
    for (int it = 0; it < 2; ++it) {
        int s = it * 512 + tid;                // chunk slot [0,1024)
        int row = s >> 3, p = s & 7;
        int c = p ^ (row & 7);
        gl16(A16 + (((size_t)(arow_base + row)) << 9) + kin + c * 8, dst + (s - lane) * 8);
    }
}

__device__ __forceinline__ void stage_B_it(const u16* __restrict__ KT, u16* dst,
                                           int n0, int kc, int it, int tid, int lane) {
    int s = it * 512 + tid;                    // chunk slot [0,2048)
    int row = s >> 3, p = s & 7;
    int c = p ^ (row & 7);
    gl16(KT + (((size_t)(n0 + row)) << 10) + kc + c * 8, dst + (s - lane) * 8);
}

__global__ __launch_bounds__(512, 2) void gemm_gates(
    const u16* __restrict__ A16, const u16* __restrict__ KT,
    const float* __restrict__ bias,
    u16* __restrict__ X, u16* __restrict__ F, float* __restrict__ O)
{
    __shared__ u16 lA[3 * LDS_A];
    __shared__ u16 lB[3 * LDS_B];

    const int tid  = threadIdx.x;
    const int lane = tid & 63;
    const int wave = tid >> 6;

    // bijective XCD swizzle: 1536 wg, 8 XCDs, 192/XCD; within an XCD nb-minor so
    // 6 consecutive blocks share one A tile; each XCD streams its own 32-mb strip,
    // KT (3MB) stays L2-resident per XCD.
    const int orig = blockIdx.x;
    const int wg = (orig & 7) * 192 + (orig >> 3);
    const int nb = wg % 6;
    const int mb = wg / 6;
    const int m0 = mb * 128;
    const int n0 = nb * 256;
    const int b  = m0 >> 12;            // 128 | 4096 -> block never straddles batches
    const int t0 = m0 & 4095;
    const int arow0 = b * (Tsz + 1) + t0;

    float4_ acc[4][4];
    #pragma unroll
    for (int i = 0; i < 4; ++i)
        #pragma unroll
        for (int j = 0; j < 4; ++j) acc[i][j] = (float4_)0.0f;

    const int wm = (wave >> 2) * 64;    // 2 m-waves
    const int wn = (wave & 3) * 64;     // 4 n-waves
    const int arow = wm + (lane & 15);
    const int brow = wn + (lane & 15);
    const int q   = lane >> 4;          // k-quad
    const int swz = lane & 7;           // == row&7 for all fragment rows

    // prologue: stage tiles 0 and 1 (12 gl16 in flight)
    stage_A(A16, lA, arow0, 0, tid, lane);
    #pragma unroll
    for (int it = 0; it < 4; ++it) stage_B_it(KT, lB, n0, 0, it, tid, lane);
    stage_A(A16, lA + LDS_A, arow0, 64, tid, lane);
    #pragma unroll
    for (int it = 0; it < 4; ++it) stage_B_it(KT, lB + LDS_B, n0, 64, it, tid, lane);

    int buf = 0;
    #pragma unroll 1
    for (int kt = 0; kt < 16; ++kt) {
        // counted gate: tile kt's 6 loads are the oldest -> vmcnt(6) retires them
        // while tile kt+1's 6 stay in flight. Drain only at the final tile.
        if (kt < 15) asm volatile("s_waitcnt vmcnt(6)" ::: "memory");
        else         asm volatile("s_waitcnt vmcnt(0)" ::: "memory");
        __builtin_amdgcn_s_barrier();   // all waves' tile-kt stages visible

        const u16* a  = lA + buf * LDS_A;
        const u16* bs = lB + buf * LDS_B;
        const int nbuf = (buf >= 1) ? buf - 1 : 2;      // (kt+2)%3
        const int kt2 = kt + 2;
        const bool st = kt2 < 16;
        const int kc2 = kt2 * 64;

        // ---- phase 1: ni 0..1 ----
        half8 fa[4][2], fb01[2][2];
        #pragma unroll
        for (int mi = 0; mi < 4; ++mi)
            #pragma unroll
            for (int s2 = 0; s2 < 2; ++s2)
                fa[mi][s2] = *(const half8*)(a + (arow + mi * 16) * 64 + (((s2 * 4 + q) ^ swz) * 8));
        #pragma unroll
        for (int ni = 0; ni < 2; ++ni)
            #pragma unroll
            for (int s2 = 0; s2 < 2; ++s2)
                fb01[ni][s2] = *(const half8*)(bs + (brow + ni * 16) * 64 + (((s2 * 4 + q) ^ swz) * 8));
        if (st) {
            stage_A(A16, lA + nbuf * LDS_A, arow0 + (kt2 >> 3), (kt2 & 7) * 64, tid, lane);
            stage_B_it(KT, lB + nbuf * LDS_B, n0, kc2, 0, tid, lane);
        }
        __builtin_amdgcn_s_barrier();
        asm volatile("s_waitcnt lgkmcnt(0)" ::: "memory");
        __builtin_amdgcn_s_setprio(1);
        #pragma unroll
        for (int s2 = 0; s2 < 2; ++s2)
            #pragma unroll
            for (int mi = 0; mi < 4; ++mi)
                #pragma unroll
                for (int ni = 0; ni < 2; ++ni)
                    acc[mi][ni] = __builtin_amdgcn_mfma_f32_16x16x32_f16(fa[mi][s2], fb01[ni][s2], acc[mi][ni], 0, 0, 0);
        __builtin_amdgcn_s_setprio(0);
        __builtin_amdgcn_s_barrier();

        // ---- phase 2: ni 2..3 (fa reused from registers) ----
        half8 fb23[2][2];
        #pragma unroll
        for (int ni = 0; ni < 2; ++ni)
            #pragma unroll
            for (int s2 = 0; s2 < 2; ++s2)
                fb23[ni][s2] = *(const half8*)(bs + (brow + 32 + ni * 16) * 64 + (((s2 * 4 + q) ^ swz) * 8));
        if (st) {
            stage_B_it(KT, lB + nbuf * LDS_B, n0, kc2, 1, tid, lane);
            stage_B_it(KT, lB + nbuf * LDS_B, n0, kc2, 2, tid, lane);
            stage_B_it(KT, lB + nbuf * LDS_B, n0, kc2, 3, tid, lane);
        }
        __builtin_amdgcn_s_barrier();
        asm volatile("s_waitcnt lgkmcnt(0)" ::: "memory");
        __builtin_amdgcn_s_setprio(1);
        #pragma unroll
        for (int s2 = 0; s2 < 2; ++s2)
            #pragma unroll
            for (int mi = 0; mi < 4; ++mi)
                #pragma unroll
                for (int ni = 0; ni < 2; ++ni)
                    acc[mi][ni + 2] = __builtin_amdgcn_mfma_f32_16x16x32_f16(fa[mi][s2], fb23[ni][s2], acc[mi][ni + 2], 0, 0, 0);
        __builtin_amdgcn_s_setprio(0);

        buf = (buf == 2) ? 0 : buf + 1;
    }

    // epilogue: bias + activation. Plane uniform per block (256 | 512).
    const int plane = nb >> 1;   // 0=X,1=F,2=O
    const int rq = q * 4;
    const int cl = lane & 15;
    #pragma unroll
    for (int mi = 0; mi < 4; ++mi)
        #pragma unroll
        for (int ni = 0; ni < 4; ++ni) {
            const int gm = m0 + wm + mi * 16 + rq;
            const int gn = n0 + wn + ni * 16 + cl;
            const float bv = bias[gn];
            const int cp = gn & 511;
            #pragma unroll
            for (int r2 = 0; r2 < 4; ++r2) {
                float v = acc[mi][ni][r2] + bv;
                if (plane == 0) {
                    float res = 1.0f - 2.0f / (__expf(2.0f * v) + 1.0f);   // tanh, overflow-safe
                    hu cv; cv.h = (f16)res;
                    X[(size_t)(gm + r2) * Usz + cp] = cv.u;
                } else if (plane == 1) {
                    float res = 1.0f / (1.0f + __expf(-v));                // sigmoid, overflow-safe
                    hu cv; cv.h = (f16)res;
                    F[(size_t)(gm + r2) * Usz + cp] = cv.u;
                } else {
                    float res = 1.0f / (1.0f + __expf(-v));
                    O[(size_t)(gm + r2) * Usz + cp] = res;
                }
            }
        }
}

__device__ __forceinline__ float4_ x4(const u16* p) {
    ushort4_ xr = *(const ushort4_*)p;
    float4_ xv;
    #pragma unroll
    for (int j = 0; j < 4; ++j) { hu cv; cv.u = xr[j]; xv[j] = (float)cv.h; }
    return xv;
}

// ---------- S1: per-chunk composites A=prod f, B=chunk applied to c=0 ----------
__global__ void scan_chunk(const u16* __restrict__ F, const u16* __restrict__ X,
                           float* __restrict__ CA, float* __restrict__ CB) {
    int g = blockIdx.x * 256 + threadIdx.x;     // 131072 = B*NCH*U/4
    int u4 = (g & 127) * 4;
    int bc = g >> 7;                             // b*NCH + ch
    size_t base = (size_t)bc * CHL * Usz + u4;
    float4_ c = (float4_)0.0f, A = (float4_)1.0f;
    for (int i = 0; i < CHL; ++i) {
        float4_ fv = x4(F + base + (size_t)i * Usz);
        float4_ xv = x4(X + base + (size_t)i * Usz);
        c = fv * c + (1.0f - fv) * xv;
        A = A * fv;
    }
    *(float4_*)(CA + (size_t)bc * Usz + u4) = A;
    *(float4_*)(CB + (size_t)bc * Usz + u4) = c;
}

// ---------- S2: sequential prefix across chunks -> chunk-start carries ----------
__global__ void scan_prefix(const float* __restrict__ CA, const float* __restrict__ CB,
                            float* __restrict__ CS) {
    int g = blockIdx.x * 256 + threadIdx.x;     // 4096 = B*U
    int u = g & 511;
    int b = g >> 9;
    float c = 0.0f;
    #pragma unroll 16
    for (int ch = 0; ch < NCH; ++ch) {
        int idx = (b * NCH + ch) * Usz + u;
        CS[idx] = c;
        c = CA[idx] * c + CB[idx];
    }
}

// ---------- S3: re-scan chunks with carry, h = sigmoid(o)*c (O in-place in out) ----------
__global__ void scan_final(const u16* __restrict__ F, const u16* __restrict__ X,
                           const float* __restrict__ CS, float* __restrict__ out) {
    int g = blockIdx.x * 256 + threadIdx.x;     // 131072
    int u4 = (g & 127) * 4;
    int bc = g >> 7;
    size_t base = (size_t)bc * CHL * Usz + u4;
    float4_ c = *(const float4_*)(CS + (size_t)bc * Usz + u4);
    for (int i = 0; i < CHL; ++i) {
        float4_ fv = x4(F + base + (size_t)i * Usz);
        float4_ xv = x4(X + base + (size_t)i * Usz);
        c = fv * c + (1.0f - fv) * xv;
        float4_ ov = *(const float4_*)(out + base + (size_t)i * Usz);  // read O before overwrite
        *(float4_*)(out + base + (size_t)i * Usz) = ov * c;
    }
}

extern "C" void kernel_launch(void* const* d_in, const int* in_sizes, int n_in,
                              void* d_out, int out_size, void* d_ws, size_t ws_size,
                              hipStream_t stream) {
    const float* in   = (const float*)d_in[0];   // [8,4096,512] fp32
    const float* kern = (const float*)d_in[1];   // [2,512,1536] fp32
    const float* bias = (const float*)d_in[2];   // [1536] fp32
    float* out = (float*)d_out;                  // [8,4096,512] fp32
    char* ws = (char*)d_ws;

    // workspace layout (~99 MB; known budget >= 110,102,528)
    const size_t A16_B  = (size_t)Bsz * (Tsz + 1) * Csz * 2;   // 33,562,624
    const size_t OFF_KT = A16_B;
    const size_t OFF_F  = OFF_KT + (size_t)NG * KK * 2;        // 36,708,352
    const size_t OFF_X  = OFF_F + (size_t)MM * Usz * 2;        // 70,262,784
    const size_t NEED   = OFF_X + (size_t)MM * Usz * 2;        // 103,817,216

    if (ws_size < NEED) return;   // guard: fail-with-poison instead of OOB fault

    u16*   A16 = (u16*)ws;
    u16*   KT  = (u16*)(ws + OFF_KT);
    u16*   Fh  = (u16*)(ws + OFF_F);
    u16*   Xb  = (u16*)(ws + OFF_X);
    // scan scratch (6 MB) aliases the A16 region: A16 is dead once gemm_gates
    // completes, and all launches are stream-ordered (graph replay preserves order).
    const size_t CH = (size_t)Bsz * NCH * Usz;   // floats per composite plane
    float* CA = (float*)ws;
    float* CB = CA + CH;
    float* CS = CB + CH;

    prep_a<<<(int)(A16_B / 16 / 256), 256, 0, stream>>>(in, A16);
    prep_k<<<dim3(KK / 64, NG / 64), 256, 0, stream>>>(kern, KT);
    gemm_gates<<<(MM / 128) * (NG / 256), 512, 0, stream>>>(A16, KT, bias, Xb, Fh, out);
    scan_chunk<<<Bsz * NCH * Usz / 4 / 256, 256, 0, stream>>>(Fh, Xb, CA, CB);
    scan_prefix<<<Bsz * Usz / 256, 256, 0, stream>>>(CA, CB, CS);
    scan_final<<<Bsz * NCH * Usz / 4 / 256, 256, 0, stream>>>(Fh, Xb, CS, out);
}

// Round 3
// 302.015 us; speedup vs baseline: 1.0497x; 1.0497x over previous
//
#include <hip/hip_runtime.h>

typedef unsigned short u16;
typedef unsigned int u32;
typedef _Float16 f16;
typedef __attribute__((ext_vector_type(8))) _Float16 half8;
typedef __attribute__((ext_vector_type(2))) __fp16 fp16x2;
typedef __attribute__((ext_vector_type(4))) float float4_;
typedef __attribute__((ext_vector_type(4))) unsigned short ushort4_;
typedef __attribute__((ext_vector_type(4))) unsigned int u32x4;

union hu { f16 h; u16 u; };

__device__ __forceinline__ u32 pkrtz(float a, float b) {
    fp16x2 t = __builtin_amdgcn_cvt_pkrtz(a, b);
    union { fp16x2 h; u32 u; } cv; cv.h = t;
    return cv.u;
}

// ---------- async global->LDS, 16B/lane ----------
__device__ __forceinline__ void gl16(const u16* g, u16* l) {
    __builtin_amdgcn_global_load_lds(
        (const __attribute__((address_space(1))) void*)g,
        (__attribute__((address_space(3))) void*)l, 16, 0, 0);
}

#define Bsz 8
#define Tsz 4096
#define Csz 512
#define Usz 512
#define NG  1536           // 3U
#define KK  1024           // 2 taps * C
#define MM  32768          // B*T
#define NCH 128            // scan chunks (2 blocks/CU in scan kernels)
#define CHL 32             // chunk length

// ---------- P0: inputs fp32 -> fp16 plane [8][4097][512], zero row at t=4096 ----------
__global__ void prep_a(const float* __restrict__ in, u16* __restrict__ A16) {
    int gid = blockIdx.x * 256 + threadIdx.x;       // 2,097,664 threads, 8 halves each
    int idx8 = gid * 8;
    int c8 = idx8 & 511;
    int row = idx8 >> 9;                            // b*4097 + t
    int b = (u32)row / 4097u;
    int t = row - b * 4097;
    u32x4 w;
    if (t == Tsz) {
        w = (u32x4)0;
    } else {
        const float* p = in + ((size_t)(b * Tsz + t) << 9) + c8;
        float4_ v0 = *(const float4_*)p;
        float4_ v1 = *(const float4_*)(p + 4);
        w.x = pkrtz(v0.x, v0.y); w.y = pkrtz(v0.z, v0.w);
        w.z = pkrtz(v1.x, v1.y); w.w = pkrtz(v1.z, v1.w);
    }
    *(u32x4*)(A16 + idx8) = w;
}

// ---------- P1: weights [K=1024][N=1536] fp32 -> transposed fp16 [N][K] ----------
// LDS 64x64 transpose: coalesced fp32 reads, 8B/lane coalesced u16 writes.
__global__ void prep_k(const float* __restrict__ kern, u16* __restrict__ KT) {
    __shared__ u16 t[64][70];                 // 70: spread banks on both phases
    const int k0 = blockIdx.x * 64;           // 16 blocks
    const int n0 = blockIdx.y * 64;           // 24 blocks
    const int tid = threadIdx.x;              // 256
    #pragma unroll
    for (int it = 0; it < 16; ++it) {
        int s = it * 256 + tid;
        int r = s >> 6;                        // k within tile
        int c = s & 63;                        // n within tile (coalesced)
        float v = kern[(size_t)(k0 + r) * NG + n0 + c];
        hu cv; cv.h = (f16)v;                  // RNE
        t[c][r] = cv.u;
    }
    __syncthreads();
    #pragma unroll
    for (int it = 0; it < 4; ++it) {
        int s = it * 256 + tid;
        int n = s >> 4;                        // row of KT tile
        int kq = (s & 15) * 4;                 // 4 u16 per lane, coalesced
        ushort4_ w;
        w.x = t[n][kq]; w.y = t[n][kq + 1]; w.z = t[n][kq + 2]; w.w = t[n][kq + 3];
        *(ushort4_*)(KT + (size_t)(n0 + n) * KK + k0 + kq) = w;
    }
}

// ---------- GEMM v3: gates = A'*K', fp16 MFMA ----------
// BM=BN=256, BK=32, 512 thr (8 waves 2Mx4N, wave tile 128x64, acc 8x4).
// Intensity 134 FLOP/B (vs 64 in R0, 85 in R2); reads/MFMA = 0.375 (m201 ratio).
// THREE LDS buffers of 32KB (96KB total): at tile kt, reads hit buf kt%3,
// in-flight writes (tile kt+1, issued during kt-1) hit (kt+1)%3, new issues
// (tile kt+2) hit (kt+2)%3 -- pairwise disjoint, race-free by construction.
// ONE barrier + ONE counted vmcnt(4) per K-tile, no in-tile barriers: waves
// free-run within a tile so the 2 waves/SIMD overlap MFMA with loads.
// BK=32 => LDS row = 64B; a wave's MFMA-frag ds_read_b128 (16 rows x 4 k-chunks)
// is a contiguous 1KB block => inherently bank-conflict-free, NO swizzle, and
// gl16 staging is linear on both sides.
#define LDS_T 8192         // u16 per buffer per operand (256 rows x 32)

__device__ __forceinline__ void stageA3(const u16* __restrict__ A16, u16* dst,
                                        int arow_base, int kin, int tid, int lane) {
    #pragma unroll
    for (int it = 0; it < 2; ++it) {
        int s = it * 512 + tid;                // chunk slot [0,1024): 256 rows x 4
        int row = s >> 2, c = s & 3;
        gl16(A16 + (((size_t)(arow_base + row)) << 9) + kin + c * 8, dst + (s - lane) * 8);
    }
}

__device__ __forceinline__ void stageB3(const u16* __restrict__ KT, u16* dst,
                                        int n0, int kk, int tid, int lane) {
    #pragma unroll
    for (int it = 0; it < 2; ++it) {
        int s = it * 512 + tid;
        int row = s >> 2, c = s & 3;
        gl16(KT + (((size_t)(n0 + row)) << 10) + kk + c * 8, dst + (s - lane) * 8);
    }
}

__global__ __launch_bounds__(512, 2) void gemm_gates(
    const u16* __restrict__ A16, const u16* __restrict__ KT,
    const float* __restrict__ bias,
    u16* __restrict__ X, u16* __restrict__ F, float* __restrict__ O)
{
    __shared__ u16 lA[3 * LDS_T];
    __shared__ u16 lB[3 * LDS_T];

    const int tid  = threadIdx.x;
    const int lane = tid & 63;
    const int wave = tid >> 6;

    // bijective XCD swizzle: 768 wg, 8 XCDs, 96/XCD; nb-minor so 6 consecutive
    // blocks share one A tile (256KB) and KT (3MB) stays L2-resident per XCD.
    const int orig = blockIdx.x;
    const int wg = (orig & 7) * 96 + (orig >> 3);
    const int nb = wg % 6;
    const int mb = wg / 6;
    const int m0 = mb * 256;
    const int n0 = nb * 256;
    const int b  = m0 >> 12;            // 256 | 4096 -> block never straddles batches
    const int t0 = m0 & 4095;
    const int arow0 = b * (Tsz + 1) + t0;

    float4_ acc[8][4];
    #pragma unroll
    for (int i = 0; i < 8; ++i)
        #pragma unroll
        for (int j = 0; j < 4; ++j) acc[i][j] = (float4_)0.0f;

    const int wm = (wave >> 2) * 128;   // 2 m-waves, 128 rows each
    const int wn = (wave & 3) * 64;     // 4 n-waves, 64 cols each
    const int fr = lane & 15;
    const int fq = lane >> 4;           // k-quad (8 halves each)

    // prologue: stage tiles 0 and 1 (8 gl16/thread in flight; order A0 B0 A1 B1)
    stageA3(A16, lA, arow0, 0, tid, lane);
    stageB3(KT, lB, n0, 0, tid, lane);
    stageA3(A16, lA + LDS_T, arow0, 32, tid, lane);
    stageB3(KT, lB + LDS_T, n0, 32, tid, lane);

    int buf = 0;
    #pragma unroll 1
    for (int kt = 0; kt < 32; ++kt) {
        // counted gate: tile kt's 4 loads are the per-wave oldest; vmcnt(4)
        // retires them while tile kt+1's 4 stay in flight. Drain only at kt=31.
        if (kt < 31) asm volatile("s_waitcnt vmcnt(4)" ::: "memory");
        else         asm volatile("s_waitcnt vmcnt(0)" ::: "memory");
        __builtin_amdgcn_s_barrier();   // all waves' tile-kt stages visible

        const u16* a  = lA + buf * LDS_T;
        const u16* bs = lB + buf * LDS_T;
        const int nbuf = (buf >= 1) ? buf - 1 : 2;      // (kt+2)%3
        const int kt2 = kt + 2;
        const int kk2 = kt2 * 32;
        const bool st = kt2 < 32;

        // ---- phase 0: rows wm..wm+63 ----
        half8 fa[4], fb[4];
        #pragma unroll
        for (int j = 0; j < 4; ++j)
            fa[j] = *(const half8*)(a + (wm + j * 16 + fr) * 32 + fq * 8);
        #pragma unroll
        for (int n = 0; n < 4; ++n)
            fb[n] = *(const half8*)(bs + (wn + n * 16 + fr) * 32 + fq * 8);
        if (st) stageA3(A16, lA + nbuf * LDS_T, arow0 + (kk2 >> 9), kk2 & 511, tid, lane);
        __builtin_amdgcn_sched_barrier(0);   // pin: loads+stage issued before MFMA cluster
        __builtin_amdgcn_s_setprio(1);
        #pragma unroll
        for (int mi = 0; mi < 4; ++mi)
            #pragma unroll
            for (int ni = 0; ni < 4; ++ni)
                acc[mi][ni] = __builtin_amdgcn_mfma_f32_16x16x32_f16(fa[mi], fb[ni], acc[mi][ni], 0, 0, 0);
        __builtin_amdgcn_s_setprio(0);

        // ---- phase 1: rows wm+64..wm+127 (fb reused from registers) ----
        half8 fa2[4];
        #pragma unroll
        for (int j = 0; j < 4; ++j)
            fa2[j] = *(const half8*)(a + (wm + 64 + j * 16 + fr) * 32 + fq * 8);
        if (st) stageB3(KT, lB + nbuf * LDS_T, n0, kk2, tid, lane);
        __builtin_amdgcn_sched_barrier(0);
        __builtin_amdgcn_s_setprio(1);
        #pragma unroll
        for (int mi = 0; mi < 4; ++mi)
            #pragma unroll
            for (int ni = 0; ni < 4; ++ni)
                acc[4 + mi][ni] = __builtin_amdgcn_mfma_f32_16x16x32_f16(fa2[mi], fb[ni], acc[4 + mi][ni], 0, 0, 0);
        __builtin_amdgcn_s_setprio(0);

        buf = (buf == 2) ? 0 : buf + 1;
    }

    // epilogue: bias + activation. Plane uniform per block (256 | 512).
    const int plane = nb >> 1;   // 0=X,1=F,2=O
    const int rq = fq * 4;
    #pragma unroll
    for (int mi = 0; mi < 8; ++mi)
        #pragma unroll
        for (int ni = 0; ni < 4; ++ni) {
            const int gm = m0 + wm + mi * 16 + rq;
            const int gn = n0 + wn + ni * 16 + fr;
            const float bv = bias[gn];
            const int cp = gn & 511;
            #pragma unroll
            for (int r2 = 0; r2 < 4; ++r2) {
                float v = acc[mi][ni][r2] + bv;
                if (plane == 0) {
                    float res = 1.0f - 2.0f / (__expf(2.0f * v) + 1.0f);   // tanh, overflow-safe
                    hu cv; cv.h = (f16)res;
                    X[(size_t)(gm + r2) * Usz + cp] = cv.u;
                } else if (plane == 1) {
                    float res = 1.0f / (1.0f + __expf(-v));                // sigmoid, overflow-safe
                    hu cv; cv.h = (f16)res;
                    F[(size_t)(gm + r2) * Usz + cp] = cv.u;
                } else {
                    float res = 1.0f / (1.0f + __expf(-v));
                    O[(size_t)(gm + r2) * Usz + cp] = res;
                }
            }
        }
}

__device__ __forceinline__ float4_ x4(const u16* p) {
    ushort4_ xr = *(const ushort4_*)p;
    float4_ xv;
    #pragma unroll
    for (int j = 0; j < 4; ++j) { hu cv; cv.u = xr[j]; xv[j] = (float)cv.h; }
    return xv;
}

// ---------- S1: per-chunk composites A=prod f, B=chunk applied to c=0 ----------
__global__ void scan_chunk(const u16* __restrict__ F, const u16* __restrict__ X,
                           float* __restrict__ CA, float* __restrict__ CB) {
    int g = blockIdx.x * 256 + threadIdx.x;     // 131072 = B*NCH*U/4
    int u4 = (g & 127) * 4;
    int bc = g >> 7;                             // b*NCH + ch
    size_t base = (size_t)bc * CHL * Usz + u4;
    float4_ c = (float4_)0.0f, A = (float4_)1.0f;
    for (int i = 0; i < CHL; ++i) {
        float4_ fv = x4(F + base + (size_t)i * Usz);
        float4_ xv = x4(X + base + (size_t)i * Usz);
        c = fv * c + (1.0f - fv) * xv;
        A = A * fv;
    }
    *(float4_*)(CA + (size_t)bc * Usz + u4) = A;
    *(float4_*)(CB + (size_t)bc * Usz + u4) = c;
}

// ---------- S2: sequential prefix across chunks -> chunk-start carries ----------
__global__ void scan_prefix(const float* __restrict__ CA, const float* __restrict__ CB,
                            float* __restrict__ CS) {
    int g = blockIdx.x * 256 + threadIdx.x;     // 4096 = B*U
    int u = g & 511;
    int b = g >> 9;
    float c = 0.0f;
    #pragma unroll 16
    for (int ch = 0; ch < NCH; ++ch) {
        int idx = (b * NCH + ch) * Usz + u;
        CS[idx] = c;
        c = CA[idx] * c + CB[idx];
    }
}

// ---------- S3: re-scan chunks with carry, h = sigmoid(o)*c (O in-place in out) ----------
__global__ void scan_final(const u16* __restrict__ F, const u16* __restrict__ X,
                           const float* __restrict__ CS, float* __restrict__ out) {
    int g = blockIdx.x * 256 + threadIdx.x;     // 131072
    int u4 = (g & 127) * 4;
    int bc = g >> 7;
    size_t base = (size_t)bc * CHL * Usz + u4;
    float4_ c = *(const float4_*)(CS + (size_t)bc * Usz + u4);
    for (int i = 0; i < CHL; ++i) {
        float4_ fv = x4(F + base + (size_t)i * Usz);
        float4_ xv = x4(X + base + (size_t)i * Usz);
        c = fv * c + (1.0f - fv) * xv;
        float4_ ov = *(const float4_*)(out + base + (size_t)i * Usz);  // read O before overwrite
        *(float4_*)(out + base + (size_t)i * Usz) = ov * c;
    }
}

extern "C" void kernel_launch(void* const* d_in, const int* in_sizes, int n_in,
                              void* d_out, int out_size, void* d_ws, size_t ws_size,
                              hipStream_t stream) {
    const float* in   = (const float*)d_in[0];   // [8,4096,512] fp32
    const float* kern = (const float*)d_in[1];   // [2,512,1536] fp32
    const float* bias = (const float*)d_in[2];   // [1536] fp32
    float* out = (float*)d_out;                  // [8,4096,512] fp32
    char* ws = (char*)d_ws;

    // workspace layout (~99 MB; known budget >= 110,102,528)
    const size_t A16_B  = (size_t)Bsz * (Tsz + 1) * Csz * 2;   // 33,562,624
    const size_t OFF_KT = A16_B;
    const size_t OFF_F  = OFF_KT + (size_t)NG * KK * 2;        // 36,708,352
    const size_t OFF_X  = OFF_F + (size_t)MM * Usz * 2;        // 70,262,784
    const size_t NEED   = OFF_X + (size_t)MM * Usz * 2;        // 103,817,216

    if (ws_size < NEED) return;   // guard: fail-with-poison instead of OOB fault

    u16*   A16 = (u16*)ws;
    u16*   KT  = (u16*)(ws + OFF_KT);
    u16*   Fh  = (u16*)(ws + OFF_F);
    u16*   Xb  = (u16*)(ws + OFF_X);
    // scan scratch (6 MB) aliases the A16 region: A16 is dead once gemm_gates
    // completes, and all launches are stream-ordered (graph replay preserves order).
    const size_t CH = (size_t)Bsz * NCH * Usz;   // floats per composite plane
    float* CA = (float*)ws;
    float* CB = CA + CH;
    float* CS = CB + CH;

    prep_a<<<(int)(A16_B / 16 / 256), 256, 0, stream>>>(in, A16);
    prep_k<<<dim3(KK / 64, NG / 64), 256, 0, stream>>>(kern, KT);
    gemm_gates<<<(MM / 256) * (NG / 256), 512, 0, stream>>>(A16, KT, bias, Xb, Fh, out);
    scan_chunk<<<Bsz * NCH * Usz / 4 / 256, 256, 0, stream>>>(Fh, Xb, CA, CB);
    scan_prefix<<<Bsz * Usz / 256, 256, 0, stream>>>(CA, CB, CS);
    scan_final<<<Bsz * NCH * Usz / 4 / 256, 256, 0, stream>>>(Fh, Xb, CS, out);
}

// Round 5
// 297.571 us; speedup vs baseline: 1.0654x; 1.0149x over previous
//
#include <hip/hip_runtime.h>

typedef unsigned short u16;
typedef unsigned int u32;
typedef _Float16 f16;
typedef __attribute__((ext_vector_type(8))) _Float16 half8;
typedef __attribute__((ext_vector_type(2))) __fp16 fp16x2;
typedef __attribute__((ext_vector_type(4))) float float4_;
typedef __attribute__((ext_vector_type(4))) unsigned short ushort4_;
typedef __attribute__((ext_vector_type(4))) unsigned int u32x4;

union hu { f16 h; u16 u; };

__device__ __forceinline__ u32 pkrtz(float a, float b) {
    fp16x2 t = __builtin_amdgcn_cvt_pkrtz(a, b);
    union { fp16x2 h; u32 u; } cv; cv.h = t;
    return cv.u;
}

// ---------- async global->LDS, 16B/lane ----------
__device__ __forceinline__ void gl16(const u16* g, u16* l) {
    __builtin_amdgcn_global_load_lds(
        (const __attribute__((address_space(1))) void*)g,
        (__attribute__((address_space(3))) void*)l, 16, 0, 0);
}

#define Bsz 8
#define Tsz 4096
#define Csz 512
#define Usz 512
#define NG  1536           // 3U
#define KK  1024           // 2 taps * C
#define MM  32768          // B*T
#define NCH 128            // scan chunks
#define CHL 32             // chunk length

// ---------- P0: inputs fp32 -> fp16 plane [8][4097][512], zero row at t=4096 ----------
__global__ void prep_a(const float* __restrict__ in, u16* __restrict__ A16) {
    int gid = blockIdx.x * 256 + threadIdx.x;       // 2,097,664 threads, 8 halves each
    int idx8 = gid * 8;
    int c8 = idx8 & 511;
    int row = idx8 >> 9;                            // b*4097 + t
    int b = (u32)row / 4097u;
    int t = row - b * 4097;
    u32x4 w;
    if (t == Tsz) {
        w = (u32x4)0;
    } else {
        const float* p = in + ((size_t)(b * Tsz + t) << 9) + c8;
        float4_ v0 = *(const float4_*)p;
        float4_ v1 = *(const float4_*)(p + 4);
        w.x = pkrtz(v0.x, v0.y); w.y = pkrtz(v0.z, v0.w);
        w.z = pkrtz(v1.x, v1.y); w.w = pkrtz(v1.z, v1.w);
    }
    *(u32x4*)(A16 + idx8) = w;
}

// ---------- P1: weights [K=1024][N=1536] fp32 -> transposed fp16 [N][K] ----------
__global__ void prep_k(const float* __restrict__ kern, u16* __restrict__ KT) {
    __shared__ u16 t[64][70];                 // 70: spread banks on both phases
    const int k0 = blockIdx.x * 64;           // 16 blocks
    const int n0 = blockIdx.y * 64;           // 24 blocks
    const int tid = threadIdx.x;              // 256
    #pragma unroll
    for (int it = 0; it < 16; ++it) {
        int s = it * 256 + tid;
        int r = s >> 6;                        // k within tile
        int c = s & 63;                        // n within tile (coalesced)
        float v = kern[(size_t)(k0 + r) * NG + n0 + c];
        hu cv; cv.h = (f16)v;                  // RNE
        t[c][r] = cv.u;
    }
    __syncthreads();
    #pragma unroll
    for (int it = 0; it < 4; ++it) {
        int s = it * 256 + tid;
        int n = s >> 4;                        // row of KT tile
        int kq = (s & 15) * 4;                 // 4 u16 per lane, coalesced
        ushort4_ w;
        w.x = t[n][kq]; w.y = t[n][kq + 1]; w.z = t[n][kq + 2]; w.w = t[n][kq + 3];
        *(ushort4_*)(KT + (size_t)(n0 + n) * KK + k0 + kq) = w;
    }
}

// ---------- GEMM v4.1: m201 8-phase port. BM=BN=256, BK=64, 512 thr, 128KB LDS ----------
// 16 K-tiles, 2 per iteration (tile parity = LDS buffer). Per tile, 4 quadrant
// phases of 16 MFMA; each phase: {ds_reads | 1 half-tile gl16 stage -> barrier ->
// lgkmcnt(0)+sched_barrier -> setprio(1) MFMA setprio(0) -> barrier}.
// vmcnt ONLY at end of P4/P8 (counted 4; drain 0 on last iter).
//
// RACE FIX (R4 post-mortem): counted vmcnt gates rely on gl16 ISSUE ORDER.
// Steady-state order is pinned because every phase boundary contains an
// inline-asm s_waitcnt with a "memory" clobber (gl16 cannot hoist above or
// sink below it). The PROLOGUE had 12 gl16 in one fence-free region -> LLVM
// may reorder them (disjoint memory) -> vmcnt(4) could leave a tile-0 load
// in flight while P1 reads it (intermittent replay corruption seen in R4).
// Fix: prologue gate is vmcnt(0) (order-insensitive; steady-state ledger
// re-derives identically) + defensive compiler fence between stage groups.
//
// Steady-state FIFO ledger per wave (2 gl16 per half-stage), prologue drained:
//   enter P1(i): outstanding = B_odd(2i+1)x4 [i>0; i=0: 0]
//   P1 +A_odd h0, P2 +A_odd h1, P3 +B_even(2i+2) h0, P4 +B_even h1
//   end-P4 vmcnt(4): retires [B_odd x4 (if any), A_odd x4] -> tile 2i+1 landed
//   P5 +A_even h0, P6 +A_even h1, P7 +B_odd(2i+3) h0, P8 +B_odd h1
//   end-P8 vmcnt(4): retires [B_even x4, A_even x4] -> tile 2i+2 landed
// Stage-target liveness: A buffers dead after P3/P7 barrier, B after P2/P6;
// every stage is issued >=1 full barrier-phase after the target's last read.
// LDS: chunk c (16B) of row r at position c^(r&7) (pre-swizzled global source,
// linear gl16 dest) -> fragment ds_read_b128 2-way max per 16-lane group = free
// (0 conflicts measured on this exact layout in R0).
#define ABUF 16384         // u16 per A buffer (256 x 64)

__device__ __forceinline__ void stageAh(const u16* __restrict__ A16, u16* dst,
                                        int arow0, int kt, int h, int tid, int lane) {
    const int tap = kt >> 3;           // 8 K-tiles per conv tap
    const int kin = (kt & 7) * 64;
    #pragma unroll
    for (int it = 0; it < 2; ++it) {
        int s = it * 512 + tid;        // [0,1024): 128 rows x 8 chunks
        int rl = s >> 3, p = s & 7;
        int c = p ^ (rl & 7);
        gl16(A16 + (((size_t)(arow0 + h * 128 + rl + tap)) << 9) + kin + c * 8,
             dst + h * 8192 + (s - lane) * 8);
    }
}

__device__ __forceinline__ void stageBh(const u16* __restrict__ KT, u16* dst,
                                        int n0, int kt, int h, int tid, int lane) {
    const int kk = kt * 64;
    #pragma unroll
    for (int it = 0; it < 2; ++it) {
        int s = it * 512 + tid;
        int rl = s >> 3, p = s & 7;
        int c = p ^ (rl & 7);
        gl16(KT + (((size_t)(n0 + h * 128 + rl)) << 10) + kk + c * 8,
             dst + h * 8192 + (s - lane) * 8);
    }
}

#define FRAG_A(buf, mh, j, ks) \
    (*(const half8*)((buf) + (wm + (mh)*64 + (j)*16 + fr) * 64 + ((((ks)*4 + fq) ^ swz) * 8)))
#define FRAG_B(buf, nh, n, ks) \
    (*(const half8*)((buf) + (wn + (nh)*32 + (n)*16 + fr) * 64 + ((((ks)*4 + fq) ^ swz) * 8)))

__global__ __launch_bounds__(512, 2) void gemm_gates(
    const u16* __restrict__ A16, const u16* __restrict__ KT,
    const float* __restrict__ bias,
    u16* __restrict__ X, u16* __restrict__ F, float* __restrict__ O)
{
    __shared__ u16 lA[2 * ABUF];    // 64 KB: even-tile buffer, odd-tile buffer
    __shared__ u16 lB[2 * ABUF];    // 64 KB

    const int tid  = threadIdx.x;
    const int lane = tid & 63;
    const int wave = tid >> 6;

    // bijective XCD swizzle: 768 wg, 8 XCDs, 96/XCD; nb-minor so 6 consecutive
    // blocks share one A strip; KT (3MB) stays L2-resident per XCD.
    const int orig = blockIdx.x;
    const int wg = (orig & 7) * 96 + (orig >> 3);
    const int nb = wg % 6;
    const int mb = wg / 6;
    const int m0 = mb * 256;
    const int n0 = nb * 256;
    const int b  = m0 >> 12;            // 256 | 4096 -> block never straddles batches
    const int t0 = m0 & 4095;
    const int arow0 = b * (Tsz + 1) + t0;

    float4_ acc[8][4];
    #pragma unroll
    for (int i = 0; i < 8; ++i)
        #pragma unroll
        for (int j = 0; j < 4; ++j) acc[i][j] = (float4_)0.0f;

    const int wm = (wave >> 2) * 128;   // 2 m-waves, 128 rows each
    const int wn = (wave & 3) * 64;     // 4 n-waves, 64 cols each
    const int fr = lane & 15;
    const int fq = lane >> 4;           // k-quad (8 halves)
    const int swz = fr & 7;             // row&7 for every fragment row (offsets %8==0)

    // prologue: tile0 A+B, tile1 B. Gate with vmcnt(0): order-insensitive
    // (see RACE FIX note). Fence between groups is defensive only.
    stageAh(A16, lA, arow0, 0, 0, tid, lane);
    stageAh(A16, lA, arow0, 0, 1, tid, lane);
    stageBh(KT, lB, n0, 0, 0, tid, lane);
    stageBh(KT, lB, n0, 0, 1, tid, lane);
    asm volatile("" ::: "memory");      // keep tile0 issues before tile1 issues
    stageBh(KT, lB + ABUF, n0, 1, 0, tid, lane);
    stageBh(KT, lB + ABUF, n0, 1, 1, tid, lane);
    asm volatile("s_waitcnt vmcnt(0)" ::: "memory");
    __builtin_amdgcn_s_barrier();

    half8 fa0[4][2], fa1[4][2], fb0[2][2], fb1[2][2];

    #pragma unroll 1
    for (int i = 0; i < 8; ++i) {
        const int tOdd = 2 * i + 1;
        const int tNx0 = 2 * i + 2;     // even tile, next pair
        const int tNx1 = 2 * i + 3;
        const bool more = (i < 7);

        // ---- P1: tile even, quad (m-low, n-low) ----
        #pragma unroll
        for (int j = 0; j < 4; ++j) { fa0[j][0] = FRAG_A(lA, 0, j, 0); fa0[j][1] = FRAG_A(lA, 0, j, 1); }
        #pragma unroll
        for (int n = 0; n < 2; ++n) { fb0[n][0] = FRAG_B(lB, 0, n, 0); fb0[n][1] = FRAG_B(lB, 0, n, 1); }
        stageAh(A16, lA + ABUF, arow0, tOdd, 0, tid, lane);
        __builtin_amdgcn_s_barrier();
        asm volatile("s_waitcnt lgkmcnt(0)" ::: "memory");
        __builtin_amdgcn_sched_barrier(0);
        __builtin_amdgcn_s_setprio(1);
        #pragma unroll
        for (int ks = 0; ks < 2; ++ks)
            #pragma unroll
            for (int mi = 0; mi < 4; ++mi)
                #pragma unroll
                for (int ni = 0; ni < 2; ++ni)
                    acc[mi][ni] = __builtin_amdgcn_mfma_f32_16x16x32_f16(fa0[mi][ks], fb0[ni][ks], acc[mi][ni], 0, 0, 0);
        __builtin_amdgcn_s_setprio(0);
        __builtin_amdgcn_s_barrier();

        // ---- P2: quad (m-low, n-high) ----
        #pragma unroll
        for (int n = 0; n < 2; ++n) { fb1[n][0] = FRAG_B(lB, 1, n, 0); fb1[n][1] = FRAG_B(lB, 1, n, 1); }
        stageAh(A16, lA + ABUF, arow0, tOdd, 1, tid, lane);
        __builtin_amdgcn_s_barrier();
        asm volatile("s_waitcnt lgkmcnt(0)" ::: "memory");
        __builtin_amdgcn_sched_barrier(0);
        __builtin_amdgcn_s_setprio(1);
        #pragma unroll
        for (int ks = 0; ks < 2; ++ks)
            #pragma unroll
            for (int mi = 0; mi < 4; ++mi)
                #pragma unroll
                for (int ni = 0; ni < 2; ++ni)
                    acc[mi][ni + 2] = __builtin_amdgcn_mfma_f32_16x16x32_f16(fa0[mi][ks], fb1[ni][ks], acc[mi][ni + 2], 0, 0, 0);
        __builtin_amdgcn_s_setprio(0);
        __builtin_amdgcn_s_barrier();

        // ---- P3: quad (m-high, n-low); B-even dead after P2 -> stage next even B ----
        #pragma unroll
        for (int j = 0; j < 4; ++j) { fa1[j][0] = FRAG_A(lA, 1, j, 0); fa1[j][1] = FRAG_A(lA, 1, j, 1); }
        if (more) stageBh(KT, lB, n0, tNx0, 0, tid, lane);
        __builtin_amdgcn_s_barrier();
        asm volatile("s_waitcnt lgkmcnt(0)" ::: "memory");
        __builtin_amdgcn_sched_barrier(0);
        __builtin_amdgcn_s_setprio(1);
        #pragma unroll
        for (int ks = 0; ks < 2; ++ks)
            #pragma unroll
            for (int mi = 0; mi < 4; ++mi)
                #pragma unroll
                for (int ni = 0; ni < 2; ++ni)
                    acc[4 + mi][ni] = __builtin_amdgcn_mfma_f32_16x16x32_f16(fa1[mi][ks], fb0[ni][ks], acc[4 + mi][ni], 0, 0, 0);
        __builtin_amdgcn_s_setprio(0);
        __builtin_amdgcn_s_barrier();

        // ---- P4: quad (m-high, n-high), no reads; vmcnt gate for P5 ----
        if (more) stageBh(KT, lB, n0, tNx0, 1, tid, lane);
        __builtin_amdgcn_s_barrier();
        __builtin_amdgcn_s_setprio(1);
        #pragma unroll
        for (int ks = 0; ks < 2; ++ks)
            #pragma unroll
            for (int mi = 0; mi < 4; ++mi)
                #pragma unroll
                for (int ni = 0; ni < 2; ++ni)
                    acc[4 + mi][ni + 2] = __builtin_amdgcn_mfma_f32_16x16x32_f16(fa1[mi][ks], fb1[ni][ks], acc[4 + mi][ni + 2], 0, 0, 0);
        __builtin_amdgcn_s_setprio(0);
        if (more) asm volatile("s_waitcnt vmcnt(4)" ::: "memory");
        else      asm volatile("s_waitcnt vmcnt(0)" ::: "memory");
        __builtin_amdgcn_s_barrier();

        // ---- P5: tile odd, quad (m-low, n-low); A-even dead after P3 ----
        #pragma unroll
        for (int j = 0; j < 4; ++j) { fa0[j][0] = FRAG_A(lA + ABUF, 0, j, 0); fa0[j][1] = FRAG_A(lA + ABUF, 0, j, 1); }
        #pragma unroll
        for (int n = 0; n < 2; ++n) { fb0[n][0] = FRAG_B(lB + ABUF, 0, n, 0); fb0[n][1] = FRAG_B(lB + ABUF, 0, n, 1); }
        if (more) stageAh(A16, lA, arow0, tNx0, 0, tid, lane);
        __builtin_amdgcn_s_barrier();
        asm volatile("s_waitcnt lgkmcnt(0)" ::: "memory");
        __builtin_amdgcn_sched_barrier(0);
        __builtin_amdgcn_s_setprio(1);
        #pragma unroll
        for (int ks = 0; ks < 2; ++ks)
            #pragma unroll
            for (int mi = 0; mi < 4; ++mi)
                #pragma unroll
                for (int ni = 0; ni < 2; ++ni)
                    acc[mi][ni] = __builtin_amdgcn_mfma_f32_16x16x32_f16(fa0[mi][ks], fb0[ni][ks], acc[mi][ni], 0, 0, 0);
        __builtin_amdgcn_s_setprio(0);
        __builtin_amdgcn_s_barrier();

        // ---- P6: quad (m-low, n-high) ----
        #pragma unroll
        for (int n = 0; n < 2; ++n) { fb1[n][0] = FRAG_B(lB + ABUF, 1, n, 0); fb1[n][1] = FRAG_B(lB + ABUF, 1, n, 1); }
        if (more) stageAh(A16, lA, arow0, tNx0, 1, tid, lane);
        __builtin_amdgcn_s_barrier();
        asm volatile("s_waitcnt lgkmcnt(0)" ::: "memory");
        __builtin_amdgcn_sched_barrier(0);
        __builtin_amdgcn_s_setprio(1);
        #pragma unroll
        for (int ks = 0; ks < 2; ++ks)
            #pragma unroll
            for (int mi = 0; mi < 4; ++mi)
                #pragma unroll
                for (int ni = 0; ni < 2; ++ni)
                    acc[mi][ni + 2] = __builtin_amdgcn_mfma_f32_16x16x32_f16(fa0[mi][ks], fb1[ni][ks], acc[mi][ni + 2], 0, 0, 0);
        __builtin_amdgcn_s_setprio(0);
        __builtin_amdgcn_s_barrier();

        // ---- P7: quad (m-high, n-low); B-odd dead after P6 ----
        #pragma unroll
        for (int j = 0; j < 4; ++j) { fa1[j][0] = FRAG_A(lA + ABUF, 1, j, 0); fa1[j][1] = FRAG_A(lA + ABUF, 1, j, 1); }
        if (more) stageBh(KT, lB + ABUF, n0, tNx1, 0, tid, lane);
        __builtin_amdgcn_s_barrier();
        asm volatile("s_waitcnt lgkmcnt(0)" ::: "memory");
        __builtin_amdgcn_sched_barrier(0);
        __builtin_amdgcn_s_setprio(1);
        #pragma unroll
        for (int ks = 0; ks < 2; ++ks)
            #pragma unroll
            for (int mi = 0; mi < 4; ++mi)
                #pragma unroll
                for (int ni = 0; ni < 2; ++ni)
                    acc[4 + mi][ni] = __builtin_amdgcn_mfma_f32_16x16x32_f16(fa1[mi][ks], fb0[ni][ks], acc[4 + mi][ni], 0, 0, 0);
        __builtin_amdgcn_s_setprio(0);
        __builtin_amdgcn_s_barrier();

        // ---- P8: quad (m-high, n-high), no reads; vmcnt gate for next P1 ----
        if (more) stageBh(KT, lB + ABUF, n0, tNx1, 1, tid, lane);
        __builtin_amdgcn_s_barrier();
        __builtin_amdgcn_s_setprio(1);
        #pragma unroll
        for (int ks = 0; ks < 2; ++ks)
            #pragma unroll
            for (int mi = 0; mi < 4; ++mi)
                #pragma unroll
                for (int ni = 0; ni < 2; ++ni)
                    acc[4 + mi][ni + 2] = __builtin_amdgcn_mfma_f32_16x16x32_f16(fa1[mi][ks], fb1[ni][ks], acc[4 + mi][ni + 2], 0, 0, 0);
        __builtin_amdgcn_s_setprio(0);
        if (more) asm volatile("s_waitcnt vmcnt(4)" ::: "memory");
        else      asm volatile("s_waitcnt vmcnt(0)" ::: "memory");
        __builtin_amdgcn_s_barrier();
    }

    // epilogue: bias + activation. Plane uniform per block (256 | 512).
    const int plane = nb >> 1;   // 0=X,1=F,2=O
    const int rq = fq * 4;
    #pragma unroll
    for (int mi = 0; mi < 8; ++mi)
        #pragma unroll
        for (int ni = 0; ni < 4; ++ni) {
            const int gm = m0 + wm + mi * 16 + rq;
            const int gn = n0 + wn + ni * 16 + fr;
            const float bv = bias[gn];
            const int cp = gn & 511;
            #pragma unroll
            for (int r2 = 0; r2 < 4; ++r2) {
                float v = acc[mi][ni][r2] + bv;
                if (plane == 0) {
                    float res = 1.0f - 2.0f / (__expf(2.0f * v) + 1.0f);   // tanh, overflow-safe
                    hu cv; cv.h = (f16)res;
                    X[(size_t)(gm + r2) * Usz + cp] = cv.u;
                } else if (plane == 1) {
                    float res = 1.0f / (1.0f + __expf(-v));                // sigmoid, overflow-safe
                    hu cv; cv.h = (f16)res;
                    F[(size_t)(gm + r2) * Usz + cp] = cv.u;
                } else {
                    float res = 1.0f / (1.0f + __expf(-v));
                    O[(size_t)(gm + r2) * Usz + cp] = res;
                }
            }
        }
}

__device__ __forceinline__ float4_ x4(const u16* p) {
    ushort4_ xr = *(const ushort4_*)p;
    float4_ xv;
    #pragma unroll
    for (int j = 0; j < 4; ++j) { hu cv; cv.u = xr[j]; xv[j] = (float)cv.h; }
    return xv;
}

// ---------- S1: per-chunk composites A=prod f, B=chunk applied to c=0 ----------
__global__ void scan_chunk(const u16* __restrict__ F, const u16* __restrict__ X,
                           float* __restrict__ CA, float* __restrict__ CB) {
    int g = blockIdx.x * 256 + threadIdx.x;     // 131072 = B*NCH*U/4
    int u4 = (g & 127) * 4;
    int bc = g >> 7;                             // b*NCH + ch
    size_t base = (size_t)bc * CHL * Usz + u4;
    float4_ c = (float4_)0.0f, A = (float4_)1.0f;
    for (int i = 0; i < CHL; ++i) {
        float4_ fv = x4(F + base + (size_t)i * Usz);
        float4_ xv = x4(X + base + (size_t)i * Usz);
        c = fv * c + (1.0f - fv) * xv;
        A = A * fv;
    }
    *(float4_*)(CA + (size_t)bc * Usz + u4) = A;
    *(float4_*)(CB + (size_t)bc * Usz + u4) = c;
}

// ---------- S2: sequential prefix across chunks -> chunk-start carries ----------
__global__ void scan_prefix(const float* __restrict__ CA, const float* __restrict__ CB,
                            float* __restrict__ CS) {
    int g = blockIdx.x * 256 + threadIdx.x;     // 4096 = B*U
    int u = g & 511;
    int b = g >> 9;
    float c = 0.0f;
    #pragma unroll 16
    for (int ch = 0; ch < NCH; ++ch) {
        int idx = (b * NCH + ch) * Usz + u;
        CS[idx] = c;
        c = CA[idx] * c + CB[idx];
    }
}

// ---------- S3: re-scan chunks with carry, h = sigmoid(o)*c (O in-place in out) ----------
__global__ void scan_final(const u16* __restrict__ F, const u16* __restrict__ X,
                           const float* __restrict__ CS, float* __restrict__ out) {
    int g = blockIdx.x * 256 + threadIdx.x;     // 131072
    int u4 = (g & 127) * 4;
    int bc = g >> 7;
    size_t base = (size_t)bc * CHL * Usz + u4;
    float4_ c = *(const float4_*)(CS + (size_t)bc * Usz + u4);
    for (int i = 0; i < CHL; ++i) {
        float4_ fv = x4(F + base + (size_t)i * Usz);
        float4_ xv = x4(X + base + (size_t)i * Usz);
        c = fv * c + (1.0f - fv) * xv;
        float4_ ov = *(const float4_*)(out + base + (size_t)i * Usz);  // read O before overwrite
        *(float4_*)(out + base + (size_t)i * Usz) = ov * c;
    }
}

extern "C" void kernel_launch(void* const* d_in, const int* in_sizes, int n_in,
                              void* d_out, int out_size, void* d_ws, size_t ws_size,
                              hipStream_t stream) {
    const float* in   = (const float*)d_in[0];   // [8,4096,512] fp32
    const float* kern = (const float*)d_in[1];   // [2,512,1536] fp32
    const float* bias = (const float*)d_in[2];   // [1536] fp32
    float* out = (float*)d_out;                  // [8,4096,512] fp32
    char* ws = (char*)d_ws;

    // workspace layout (~99 MB; known budget >= 110,102,528)
    const size_t A16_B  = (size_t)Bsz * (Tsz + 1) * Csz * 2;   // 33,562,624
    const size_t OFF_KT = A16_B;
    const size_t OFF_F  = OFF_KT + (size_t)NG * KK * 2;        // 36,708,352
    const size_t OFF_X  = OFF_F + (size_t)MM * Usz * 2;        // 70,262,784
    const size_t NEED   = OFF_X + (size_t)MM * Usz * 2;        // 103,817,216

    if (ws_size < NEED) return;   // guard: fail-with-poison instead of OOB fault

    u16*   A16 = (u16*)ws;
    u16*   KT  = (u16*)(ws + OFF_KT);
    u16*   Fh  = (u16*)(ws + OFF_F);
    u16*   Xb  = (u16*)(ws + OFF_X);
    // scan scratch (6 MB) aliases the A16 region: A16 is dead once gemm_gates
    // completes, and all launches are stream-ordered (graph replay preserves order).
    const size_t CH = (size_t)Bsz * NCH * Usz;   // floats per composite plane
    float* CA = (float*)ws;
    float* CB = CA + CH;
    float* CS = CB + CH;

    prep_a<<<(int)(A16_B / 16 / 256), 256, 0, stream>>>(in, A16);
    prep_k<<<dim3(KK / 64, NG / 64), 256, 0, stream>>>(kern, KT);
    gemm_gates<<<(MM / 256) * (NG / 256), 512, 0, stream>>>(A16, KT, bias, Xb, Fh, out);
    scan_chunk<<<Bsz * NCH * Usz / 4 / 256, 256, 0, stream>>>(Fh, Xb, CA, CB);
    scan_prefix<<<Bsz * Usz / 256, 256, 0, stream>>>(CA, CB, CS);
    scan_final<<<Bsz * NCH * Usz / 4 / 256, 256, 0, stream>>>(Fh, Xb, CS, out);
}

// Round 6
// 292.578 us; speedup vs baseline: 1.0836x; 1.0171x over previous
//
#include <hip/hip_runtime.h>

typedef unsigned short u16;
typedef unsigned int u32;
typedef _Float16 f16;
typedef __attribute__((ext_vector_type(8))) _Float16 half8;
typedef __attribute__((ext_vector_type(2))) __fp16 fp16x2;
typedef __attribute__((ext_vector_type(4))) float float4_;
typedef __attribute__((ext_vector_type(4))) unsigned short ushort4_;
typedef __attribute__((ext_vector_type(4))) unsigned int u32x4;

union hu { f16 h; u16 u; };

__device__ __forceinline__ u32 pkrtz(float a, float b) {
    fp16x2 t = __builtin_amdgcn_cvt_pkrtz(a, b);
    union { fp16x2 h; u32 u; } cv; cv.h = t;
    return cv.u;
}

// ---------- async global->LDS, 16B/lane ----------
__device__ __forceinline__ void gl16(const u16* g, u16* l) {
    __builtin_amdgcn_global_load_lds(
        (const __attribute__((address_space(1))) void*)g,
        (__attribute__((address_space(3))) void*)l, 16, 0, 0);
}

#define Bsz 8
#define Tsz 4096
#define Csz 512
#define Usz 512
#define NG  1536           // 3U
#define KK  1024           // 2 taps * C
#define MM  32768          // B*T
#define NCH 128            // scan chunks (2 blocks/CU in scan kernels)
#define CHL 32             // chunk length

// ---------- P0: inputs fp32 -> fp16 plane [8][4097][512], zero row at t=4096 ----------
__global__ void prep_a(const float* __restrict__ in, u16* __restrict__ A16) {
    int gid = blockIdx.x * 256 + threadIdx.x;       // 2,097,664 threads, 8 halves each
    int idx8 = gid * 8;
    int c8 = idx8 & 511;
    int row = idx8 >> 9;                            // b*4097 + t
    int b = (u32)row / 4097u;
    int t = row - b * 4097;
    u32x4 w;
    if (t == Tsz) {
        w = (u32x4)0;
    } else {
        const float* p = in + ((size_t)(b * Tsz + t) << 9) + c8;
        float4_ v0 = *(const float4_*)p;
        float4_ v1 = *(const float4_*)(p + 4);
        w.x = pkrtz(v0.x, v0.y); w.y = pkrtz(v0.z, v0.w);
        w.z = pkrtz(v1.x, v1.y); w.w = pkrtz(v1.z, v1.w);
    }
    *(u32x4*)(A16 + idx8) = w;
}

// ---------- P1: weights [K=1024][N=1536] fp32 -> transposed fp16 [N][K] ----------
// LDS 64x64 transpose: coalesced fp32 reads, 8B/lane coalesced u16 writes.
__global__ void prep_k(const float* __restrict__ kern, u16* __restrict__ KT) {
    __shared__ u16 t[64][70];                 // 70: spread banks on both phases
    const int k0 = blockIdx.x * 64;           // 16 blocks
    const int n0 = blockIdx.y * 64;           // 24 blocks
    const int tid = threadIdx.x;              // 256
    #pragma unroll
    for (int it = 0; it < 16; ++it) {
        int s = it * 256 + tid;
        int r = s >> 6;                        // k within tile
        int c = s & 63;                        // n within tile (coalesced)
        float v = kern[(size_t)(k0 + r) * NG + n0 + c];
        hu cv; cv.h = (f16)v;                  // RNE
        t[c][r] = cv.u;
    }
    __syncthreads();
    #pragma unroll
    for (int it = 0; it < 4; ++it) {
        int s = it * 256 + tid;
        int n = s >> 4;                        // row of KT tile
        int kq = (s & 15) * 4;                 // 4 u16 per lane, coalesced
        ushort4_ w;
        w.x = t[n][kq]; w.y = t[n][kq + 1]; w.z = t[n][kq + 2]; w.w = t[n][kq + 3];
        *(ushort4_*)(KT + (size_t)(n0 + n) * KK + k0 + kq) = w;
    }
}

// ---------- GEMM (R0-proven core): gates = A'*K', fp16 MFMA, BK=64, XOR-swizzled LDS ----------
// CONSOLIDATION (R5 post-mortem): the 8-phase ports (R3: 222us/19%, R5: 230us/18%)
// both lose to this simple 2-barrier 128^2 structure (136us/35.7% MfmaUtil) --
// its 4-5 blocks/CU of TLP hides what the 1-block/CU phase-lockstep exposes.
// Reverted byte-for-byte to R0 EXCEPT the block-index mapping, which becomes the
// bijective XCD swizzle (proven in R2/R5: FETCH 278MB -> 58-92MB).
// A' row m = concat(A16[b][t], A16[b][t+1]) (zero row materialized in prep_a).
// Epilogue: X=fp16(tanh(g0)), F=fp16(sigmoid(g1)), O=sigmoid(g2) fp32 -> d_out.
__global__ __launch_bounds__(256, 4) void gemm_gates(
    const u16* __restrict__ A16, const u16* __restrict__ KT,
    const float* __restrict__ bias,
    u16* __restrict__ X, u16* __restrict__ F, float* __restrict__ O)
{
    // Tiles [128 rows][64 halves]; 16B chunk c of row r stored at position c ^ (r&7)
    // -> every ds_read_b128 hits the 8-words/bank wave64 floor (0 conflicts, R0).
    __shared__ u16 lA[8192], lB[8192];

    const int tid  = threadIdx.x;
    const int lane = tid & 63;
    const int wave = tid >> 6;

    // bijective XCD swizzle: 3072 wg = 8 XCDs x 384; nb-minor within an XCD so
    // 12 consecutive blocks share one 256KB A tile (L2-hit x12) and KT (3MB)
    // stays L2-resident per XCD.
    const int orig = blockIdx.x;
    const int wg = (orig & 7) * 384 + (orig >> 3);
    const int nb = wg % 12;
    const int mb = wg / 12;
    const int m0 = mb * 128;
    const int n0 = nb * 128;
    const int b  = m0 >> 12;            // 128 | 4096 -> block never straddles batches
    const int t0 = m0 & 4095;
    const int arow0 = b * (Tsz + 1) + t0;

    float4_ acc[4][4];
    #pragma unroll
    for (int i = 0; i < 4; ++i)
        #pragma unroll
        for (int j = 0; j < 4; ++j) acc[i][j] = (float4_)0.0f;

    const int wm = (wave >> 1) * 64;
    const int wn = (wave & 1) * 64;
    const int ar = wm + (lane & 15);
    const int br = wn + (lane & 15);
    const int q  = lane >> 4;           // k-quad
    const int swz = lane & 7;           // == ar&7 == br&7 (wm,wn multiples of 64)

    for (int kc = 0; kc < KK; kc += 64) {
        __syncthreads();   // protect LDS from previous iteration's readers
        const int tap = kc >> 9;
        const int kin = kc & 511;
        const int ab = arow0 + tap;
        // --- A staging: 128x64 fp16 = 16KB, 4 gl16 iters, XOR-permuted source ---
        #pragma unroll
        for (int it = 0; it < 4; ++it) {
            const int s = it * 256 + tid;          // chunk slot [0,1024)
            const int row = s >> 3, p = s & 7;
            const int c = p ^ (row & 7);
            gl16(A16 + (((size_t)(ab + row)) << 9) + kin + c * 8, lA + (s - lane) * 8);
        }
        // --- B staging: 128x64 fp16 = 16KB ---
        #pragma unroll
        for (int it = 0; it < 4; ++it) {
            const int s = it * 256 + tid;
            const int row = s >> 3, p = s & 7;
            const int c = p ^ (row & 7);
            gl16(KT + (((size_t)(n0 + row)) << 10) + kc + c * 8, lB + (s - lane) * 8);
        }
        __syncthreads();   // staging complete (barrier drains vmcnt)

        #pragma unroll
        for (int s2 = 0; s2 < 2; ++s2) {
            half8 fa[4], fb[4];
            const int cc = (s2 * 4 + q) ^ swz;     // swizzled chunk position
            #pragma unroll
            for (int i = 0; i < 4; ++i) {
                fa[i] = *(const half8*)(lA + (ar + i * 16) * 64 + cc * 8);
                fb[i] = *(const half8*)(lB + (br + i * 16) * 64 + cc * 8);
            }
            #pragma unroll
            for (int mi = 0; mi < 4; ++mi)
                #pragma unroll
                for (int ni = 0; ni < 4; ++ni)
                    acc[mi][ni] = __builtin_amdgcn_mfma_f32_16x16x32_f16(fa[mi], fb[ni], acc[mi][ni], 0, 0, 0);
        }
    }

    // epilogue: bias + activation. Plane uniform per block (128 | 512).
    const int plane = nb >> 2;   // 0=X,1=F,2=O
    const int rq = q * 4;
    const int cl = lane & 15;
    #pragma unroll
    for (int mi = 0; mi < 4; ++mi)
        #pragma unroll
        for (int ni = 0; ni < 4; ++ni) {
            const int gm = m0 + wm + mi * 16 + rq;
            const int gn = n0 + wn + ni * 16 + cl;
            const float bv = bias[gn];
            const int cp = gn & 511;
            #pragma unroll
            for (int r2 = 0; r2 < 4; ++r2) {
                float v = acc[mi][ni][r2] + bv;
                if (plane == 0) {
                    float res = 1.0f - 2.0f / (__expf(2.0f * v) + 1.0f);   // tanh, overflow-safe
                    hu cv; cv.h = (f16)res;
                    X[(size_t)(gm + r2) * Usz + cp] = cv.u;
                } else if (plane == 1) {
                    float res = 1.0f / (1.0f + __expf(-v));                // sigmoid, overflow-safe
                    hu cv; cv.h = (f16)res;
                    F[(size_t)(gm + r2) * Usz + cp] = cv.u;
                } else {
                    float res = 1.0f / (1.0f + __expf(-v));
                    O[(size_t)(gm + r2) * Usz + cp] = res;
                }
            }
        }
}

__device__ __forceinline__ float4_ x4(const u16* p) {
    ushort4_ xr = *(const ushort4_*)p;
    float4_ xv;
    #pragma unroll
    for (int j = 0; j < 4; ++j) { hu cv; cv.u = xr[j]; xv[j] = (float)cv.h; }
    return xv;
}

// ---------- S1: per-chunk composites A=prod f, B=chunk applied to c=0 ----------
__global__ void scan_chunk(const u16* __restrict__ F, const u16* __restrict__ X,
                           float* __restrict__ CA, float* __restrict__ CB) {
    int g = blockIdx.x * 256 + threadIdx.x;     // 131072 = B*NCH*U/4
    int u4 = (g & 127) * 4;
    int bc = g >> 7;                             // b*NCH + ch
    size_t base = (size_t)bc * CHL * Usz + u4;
    float4_ c = (float4_)0.0f, A = (float4_)1.0f;
    for (int i = 0; i < CHL; ++i) {
        float4_ fv = x4(F + base + (size_t)i * Usz);
        float4_ xv = x4(X + base + (size_t)i * Usz);
        c = fv * c + (1.0f - fv) * xv;
        A = A * fv;
    }
    *(float4_*)(CA + (size_t)bc * Usz + u4) = A;
    *(float4_*)(CB + (size_t)bc * Usz + u4) = c;
}

// ---------- S2: sequential prefix across chunks -> chunk-start carries ----------
__global__ void scan_prefix(const float* __restrict__ CA, const float* __restrict__ CB,
                            float* __restrict__ CS) {
    int g = blockIdx.x * 256 + threadIdx.x;     // 4096 = B*U
    int u = g & 511;
    int b = g >> 9;
    float c = 0.0f;
    #pragma unroll 16
    for (int ch = 0; ch < NCH; ++ch) {
        int idx = (b * NCH + ch) * Usz + u;
        CS[idx] = c;
        c = CA[idx] * c + CB[idx];
    }
}

// ---------- S3: re-scan chunks with carry, h = sigmoid(o)*c (O in-place in out) ----------
__global__ void scan_final(const u16* __restrict__ F, const u16* __restrict__ X,
                           const float* __restrict__ CS, float* __restrict__ out) {
    int g = blockIdx.x * 256 + threadIdx.x;     // 131072
    int u4 = (g & 127) * 4;
    int bc = g >> 7;
    size_t base = (size_t)bc * CHL * Usz + u4;
    float4_ c = *(const float4_*)(CS + (size_t)bc * Usz + u4);
    for (int i = 0; i < CHL; ++i) {
        float4_ fv = x4(F + base + (size_t)i * Usz);
        float4_ xv = x4(X + base + (size_t)i * Usz);
        c = fv * c + (1.0f - fv) * xv;
        float4_ ov = *(const float4_*)(out + base + (size_t)i * Usz);  // read O before overwrite
        *(float4_*)(out + base + (size_t)i * Usz) = ov * c;
    }
}

extern "C" void kernel_launch(void* const* d_in, const int* in_sizes, int n_in,
                              void* d_out, int out_size, void* d_ws, size_t ws_size,
                              hipStream_t stream) {
    const float* in   = (const float*)d_in[0];   // [8,4096,512] fp32
    const float* kern = (const float*)d_in[1];   // [2,512,1536] fp32
    const float* bias = (const float*)d_in[2];   // [1536] fp32
    float* out = (float*)d_out;                  // [8,4096,512] fp32
    char* ws = (char*)d_ws;

    // workspace layout (~99 MB; known budget >= 110,102,528)
    const size_t A16_B  = (size_t)Bsz * (Tsz + 1) * Csz * 2;   // 33,562,624
    const size_t OFF_KT = A16_B;
    const size_t OFF_F  = OFF_KT + (size_t)NG * KK * 2;        // 36,708,352
    const size_t OFF_X  = OFF_F + (size_t)MM * Usz * 2;        // 70,262,784
    const size_t NEED   = OFF_X + (size_t)MM * Usz * 2;        // 103,817,216

    if (ws_size < NEED) return;   // guard: fail-with-poison instead of OOB fault

    u16*   A16 = (u16*)ws;
    u16*   KT  = (u16*)(ws + OFF_KT);
    u16*   Fh  = (u16*)(ws + OFF_F);
    u16*   Xb  = (u16*)(ws + OFF_X);
    // scan scratch (6 MB) aliases the A16 region: A16 is dead once gemm_gates
    // completes, and all launches are stream-ordered (graph replay preserves order;
    // prep_a fully rewrites the region at the start of every replay).
    const size_t CH = (size_t)Bsz * NCH * Usz;   // floats per composite plane
    float* CA = (float*)ws;
    float* CB = CA + CH;
    float* CS = CB + CH;

    prep_a<<<(int)(A16_B / 16 / 256), 256, 0, stream>>>(in, A16);
    prep_k<<<dim3(KK / 64, NG / 64), 256, 0, stream>>>(kern, KT);
    gemm_gates<<<(MM / 128) * (NG / 128), 256, 0, stream>>>(A16, KT, bias, Xb, Fh, out);
    scan_chunk<<<Bsz * NCH * Usz / 4 / 256, 256, 0, stream>>>(Fh, Xb, CA, CB);
    scan_prefix<<<Bsz * Usz / 256, 256, 0, stream>>>(CA, CB, CS);
    scan_final<<<Bsz * NCH * Usz / 4 / 256, 256, 0, stream>>>(Fh, Xb, CS, out);
}